// Round 11
// baseline (892.522 us; speedup 1.0000x reference)
//
#include <hip/hip_runtime.h>
#include <stdint.h>

#define N 8192
#define D 512
#define NEG -1e30f

typedef _Float16 f16;
typedef f16 f16x4 __attribute__((ext_vector_type(4)));
typedef f16 f16x8 __attribute__((ext_vector_type(8)));
typedef float f32x4v __attribute__((ext_vector_type(4)));
typedef float f32x16 __attribute__((ext_vector_type(16)));
typedef unsigned long long u64;

// ---- workspace layout (bytes) ----
#define XH_OFF   0ull
#define WQH_OFF  (XH_OFF + 8192ull * 512 * 2)
#define WKH_OFF  (WQH_OFF + 512ull * 512 * 2)
#define WVH_OFF  (WKH_OFF + 512ull * 512 * 2)
#define QH_OFF   (WVH_OFF + 512ull * 512 * 2)
#define KH_OFF   (QH_OFF + 8192ull * 512 * 2)
#define VT_OFF   (KH_OFF + 8192ull * 512 * 2)
#define PART_SZ  (8192ull * 512 * 2)                // one fp16 partial, 8 MB
#define P123_OFF (VT_OFF + 8192ull * 512 * 2)
#define ML_SZ    (4ull * N * 8)                     // float2[4][N]
#define ADJ_SZ   (128ull * N * 8)                   // u64 bitmap, 8 MB

// ---- attn_v5 LDS (static, 43,008 B -> 3 blocks/CU) ----
#define QROW 1040
#define PROW 272

// ---------------- fp32 -> fp16 conversion ----------------
__global__ __launch_bounds__(256) void cvt_fp16(
    const float* __restrict__ X,
    const float* __restrict__ Wq, const float* __restrict__ Wk, const float* __restrict__ Wv,
    f16* __restrict__ Xh,
    f16* __restrict__ Wqh, f16* __restrict__ Wkh, f16* __restrict__ Wvh)
{
    const int idx = blockIdx.x * 256 + threadIdx.x;
    const float* src; f16* dst; int off;
    if (idx < 1048576)      { src = X;  dst = Xh;  off = idx; }
    else if (idx < 1114112) { src = Wq; dst = Wqh; off = idx - 1048576; }
    else if (idx < 1179648) { src = Wk; dst = Wkh; off = idx - 1114112; }
    else                    { src = Wv; dst = Wvh; off = idx - 1179648; }
    const float4 v = ((const float4*)src)[off];
    f16x4 h; h.x = (f16)v.x; h.y = (f16)v.y; h.z = (f16)v.z; h.w = (f16)v.w;
    *(f16x4*)(dst + (size_t)off * 4) = h;
}

// ---------------- QKV via MFMA (unchanged) ----------------
__global__ __launch_bounds__(256) void qkv_mfma(
    const f16* __restrict__ Xh,
    const f16* __restrict__ Wqh, const f16* __restrict__ Wkh, const f16* __restrict__ Wvh,
    f16* __restrict__ qh, f16* __restrict__ kh, f16* __restrict__ vt)
{
    const int t    = threadIdx.x;
    const int w    = t >> 6;
    const int lane = t & 63;
    const int lo   = lane & 31;
    const int hi   = lane >> 5;
    const int z    = blockIdx.z;

    int m0, c0; const f16 *Ap, *Bp; f16* Yp; size_t ldy;
    if (z == 2) {
        m0 = blockIdx.x * 128 + w * 32; c0 = blockIdx.y * 128;
        Ap = Wvh; Bp = Xh; Yp = vt; ldy = N;
    } else {
        m0 = blockIdx.y * 128 + w * 32; c0 = blockIdx.x * 128;
        Ap = Xh; Bp = z ? Wkh : Wqh; Yp = z ? kh : qh; ldy = D;
    }

    const f16* arow = Ap + (size_t)(m0 + lo) * D + hi * 8;
    const f16* brow[4];
#pragma unroll
    for (int nn = 0; nn < 4; ++nn)
        brow[nn] = Bp + (size_t)(c0 + nn * 32 + lo) * D + hi * 8;

    f32x16 acc[4];
#pragma unroll
    for (int nn = 0; nn < 4; ++nn)
#pragma unroll
        for (int e = 0; e < 16; ++e) acc[nn][e] = 0.f;

#pragma unroll 4
    for (int ks = 0; ks < 32; ++ks) {
        const f16x8 a = *(const f16x8*)(arow + ks * 16);
#pragma unroll
        for (int nn = 0; nn < 4; ++nn) {
            const f16x8 b = *(const f16x8*)(brow[nn] + ks * 16);
            acc[nn] = __builtin_amdgcn_mfma_f32_32x32x16_f16(a, b, acc[nn], 0, 0, 0);
        }
    }

#pragma unroll
    for (int nn = 0; nn < 4; ++nn)
#pragma unroll
        for (int r = 0; r < 16; ++r) {
            const int row = m0 + (r & 3) + 8 * (r >> 2) + 4 * hi;
            Yp[(size_t)row * ldy + c0 + nn * 32 + lo] = (f16)acc[nn][r];
        }
}

// ---------------- adjacency bit-pack: adjb[widx][j] bit b = adj[widx*64+b][j] ----------------
// grid (128, 2), 256 thr. Wave reads 64 rows (lane=i-offset) x 1024 j; __ballot packs.
__global__ __launch_bounds__(256) void pack_adj(
    const int* __restrict__ adj, u64* __restrict__ adjb)
{
    const int widx = blockIdx.x;
    const int wv   = threadIdx.x >> 6;
    const int lane = threadIdx.x & 63;
    const int jb   = blockIdx.y * 4096 + wv * 1024;
    const int* src = adj + (size_t)(widx * 64 + lane) * N;
    u64* dst = adjb + (size_t)widx * N;
    for (int jj = 0; jj < 1024; ++jj) {
        const int j = jb + jj;
        const u64 m = __ballot(src[j] != 0);
        if (lane == 0) dst[j] = m;
    }
}

// ---------------- attention v5: 2-barrier cooperative, BJ=32 / BI=128 ----------------
// grid = 256 j-tiles x nib i-blocks. 256 thr / 4 waves.
// QK^T: wave w = i-band w*32 (A=K global 16rowx64B, B=Q LDS). Stats: band-local
// shfl -> LDS -> barrier -> EVERY lane redundantly combines j=l&31, m/l in regs;
// P-fix & rescale factors via intra-wave shfl (no 2nd exchange barrier).
// PV: wave w = d-band w*128 (A=P LDS slab, B=V^T global 16rowx64B).
__global__ __launch_bounds__(256, 3) void attn_v5(
    const f16* __restrict__ qh, const f16* __restrict__ kh,
    const f16* __restrict__ vt, const u64* __restrict__ adjb,
    f16* __restrict__ part0, f16* __restrict__ part123, float2* __restrict__ ml)
{
    __shared__ char  Qs[32 * QROW];     // 33,280
    __shared__ char  Psb[32 * PROW];    //  8,704
    __shared__ float mstat[4 * 32];
    __shared__ float lstat[4 * 32];

    const int t  = threadIdx.x;
    const int w  = t >> 6;
    const int l  = t & 63;
    const int cl = l & 15;
    const int hq = l >> 4;

    // XCD-aware mapping
    const int nib = gridDim.x >> 8;          // 4 or 2
    const int b   = blockIdx.x;
    const int xcd = b & 7;
    const int u   = b >> 3;
    int ib, jt_;
    if (nib == 4) { ib = xcd >> 1; jt_ = (xcd & 1) * 128 + u; }
    else          { ib = xcd >> 2; jt_ = (xcd & 3) * 64 + u; }
    const int j0    = jt_ * 32;
    const int ibase = ib * (N / nib);
    const int iters = (N / nib) >> 7;        // BI=128: 16 or 32

    f16* pb = (ib == 0) ? part0 : part123 + (size_t)(ib - 1) * ((size_t)N * D);

    // ---- stage Q[j0..j0+31] ----
    for (int c = t; c < 32 * 64; c += 256) {
        const int row = c >> 6, off = c & 63;
        f16x8 v = *(const f16x8*)(qh + (size_t)(j0 + row) * D + off * 8);
        *(f16x8*)(Qs + row * QROW + off * 16) = v;
    }
    __syncthreads();

    float m_run = NEG, l_run = 0.f;          // per-lane stats for j = l&31 (all waves redundant)

    f32x4v oacc[2][8];                       // [jt][dt], 64 VGPR
#pragma unroll
    for (int jt = 0; jt < 2; ++jt)
#pragma unroll
        for (int dt = 0; dt < 8; ++dt) {
            oacc[jt][dt][0] = 0.f; oacc[jt][dt][1] = 0.f;
            oacc[jt][dt][2] = 0.f; oacc[jt][dt][3] = 0.f;
        }

    for (int it = 0; it < iters; ++it) {
        const int i0t   = ibase + it * 128;
        const int iband = i0t + w * 32;

        // ---- adjacency bitmap words (L2-resident, broadcast) ----
        const u64* ab = adjb + (size_t)(iband >> 6) * N + j0;
        const u64 wd0 = ab[cl];
        const u64 wd1 = ab[16 + cl];
        const int hsh = (w & 1) * 32;

        // ---- QK^T: S^T[i-band 32][j 32] ----
        f32x4v sacc[2][2];                   // [it2][jt]
#pragma unroll
        for (int a = 0; a < 2; ++a)
#pragma unroll
            for (int c2 = 0; c2 < 2; ++c2) {
                sacc[a][c2][0] = 0.f; sacc[a][c2][1] = 0.f;
                sacc[a][c2][2] = 0.f; sacc[a][c2][3] = 0.f;
            }
        const f16* kp = kh + (size_t)(iband + cl) * D + hq * 8;
#pragma unroll 4
        for (int ks = 0; ks < 16; ++ks) {
            const f16x8 kf0 = *(const f16x8*)(kp + ks * 32);
            const f16x8 kf1 = *(const f16x8*)(kp + (size_t)16 * D + ks * 32);
            const f16x8 qf0 = *(const f16x8*)(Qs + cl * QROW + ks * 64 + hq * 16);
            const f16x8 qf1 = *(const f16x8*)(Qs + (16 + cl) * QROW + ks * 64 + hq * 16);
            sacc[0][0] = __builtin_amdgcn_mfma_f32_16x16x32_f16(kf0, qf0, sacc[0][0], 0, 0, 0);
            sacc[0][1] = __builtin_amdgcn_mfma_f32_16x16x32_f16(kf0, qf1, sacc[0][1], 0, 0, 0);
            sacc[1][0] = __builtin_amdgcn_mfma_f32_16x16x32_f16(kf1, qf0, sacc[1][0], 0, 0, 0);
            sacc[1][1] = __builtin_amdgcn_mfma_f32_16x16x32_f16(kf1, qf1, sacc[1][1], 0, 0, 0);
        }

        // ---- mask + band stats + p (band = this wave's 32 i) ----
        float p[2][2][4];                    // [it2][jt][r]
        float m4[2], pl[2];
#pragma unroll
        for (int jt = 0; jt < 2; ++jt) {
            const u64 wd = jt ? wd1 : wd0;
            const uint32_t half_ = (uint32_t)(wd >> hsh);
            float s[2][4];
#pragma unroll
            for (int it2 = 0; it2 < 2; ++it2) {
                const uint32_t sub = half_ >> (it2 * 16 + hq * 4);
#pragma unroll
                for (int r = 0; r < 4; ++r)
                    s[it2][r] = ((sub >> r) & 1) ? sacc[it2][jt][r] : NEG;
            }
            float m = NEG;
#pragma unroll
            for (int it2 = 0; it2 < 2; ++it2)
#pragma unroll
                for (int r = 0; r < 4; ++r) m = fmaxf(m, s[it2][r]);
            m = fmaxf(m, __shfl_xor(m, 16, 64));
            m = fmaxf(m, __shfl_xor(m, 32, 64));
            m4[jt] = m;
            float ps = 0.f;
#pragma unroll
            for (int it2 = 0; it2 < 2; ++it2)
#pragma unroll
                for (int r = 0; r < 4; ++r) {
                    const float pe = (s[it2][r] > -1e29f) ? __expf(s[it2][r] - m) : 0.f;
                    p[it2][jt][r] = pe;
                    ps += pe;
                }
            ps += __shfl_xor(ps, 16, 64);
            ps += __shfl_xor(ps, 32, 64);
            pl[jt] = ps;
        }
        if (l < 16) {
            mstat[w * 32 + l]      = m4[0]; lstat[w * 32 + l]      = pl[0];
            mstat[w * 32 + 16 + l] = m4[1]; lstat[w * 32 + 16 + l] = pl[1];
        }
        __syncthreads();                     // [A] stats visible

        // ---- redundant combine for j = l&31 (regs, every wave identical) ----
        {
            const int jj = l & 31;
            const float b0 = mstat[jj],       s0 = lstat[jj];
            const float b1 = mstat[32 + jj],  s1 = lstat[32 + jj];
            const float b2 = mstat[64 + jj],  s2 = lstat[64 + jj];
            const float b3 = mstat[96 + jj],  s3 = lstat[96 + jj];
            const float mn = fmaxf(m_run, fmaxf(fmaxf(b0, b1), fmaxf(b2, b3)));
            const float sc = __expf(m_run - mn);
            l_run = l_run * sc + s0 * __expf(b0 - mn) + s1 * __expf(b1 - mn)
                                + s2 * __expf(b2 - mn) + s3 * __expf(b3 - mn);
            m_run = mn;

            // ---- P write (fix band p to global max) ----
#pragma unroll
            for (int jt = 0; jt < 2; ++jt) {
                const float mnj = __shfl(mn, jt * 16 + cl, 64);
                const float f   = __expf(m4[jt] - mnj);
#pragma unroll
                for (int it2 = 0; it2 < 2; ++it2) {
                    union { f16 h[4]; uint2 u2; } pc;
#pragma unroll
                    for (int r = 0; r < 4; ++r) pc.h[r] = (f16)(p[it2][jt][r] * f);
                    *(uint2*)(Psb + (jt * 16 + cl) * PROW +
                              (w * 32 + it2 * 16 + hq * 4) * 2) = pc.u2;
                }
            }

            // ---- rescale O rows (factor via shfl) ----
#pragma unroll
            for (int jt = 0; jt < 2; ++jt)
#pragma unroll
                for (int r = 0; r < 4; ++r) {
                    const float scr = __shfl(sc, jt * 16 + hq * 4 + r, 64);
#pragma unroll
                    for (int dt = 0; dt < 8; ++dt) oacc[jt][dt][r] *= scr;
                }
        }
        __syncthreads();                     // [B] P ready

        // ---- PV: wave d-band w*128 ----
        f16x8 pa[2][4];                      // [jt][k2]
#pragma unroll
        for (int jt = 0; jt < 2; ++jt)
#pragma unroll
            for (int k2 = 0; k2 < 4; ++k2)
                pa[jt][k2] = *(const f16x8*)(Psb + (jt * 16 + cl) * PROW + k2 * 64 + hq * 16);

#pragma unroll
        for (int dt = 0; dt < 8; ++dt) {
            const f16* vp = vt + (size_t)(w * 128 + dt * 16 + cl) * N + i0t + hq * 8;
#pragma unroll
            for (int k2 = 0; k2 < 4; ++k2) {
                const f16x8 vf = *(const f16x8*)(vp + k2 * 32);
#pragma unroll
                for (int jt = 0; jt < 2; ++jt)
                    oacc[jt][dt] = __builtin_amdgcn_mfma_f32_16x16x32_f16(pa[jt][k2], vf, oacc[jt][dt], 0, 0, 0);
            }
        }
        __syncthreads();                     // P consumed (next tile may overwrite)
    }

    // ---- store fp16 unnormalized partial ----
#pragma unroll
    for (int jt = 0; jt < 2; ++jt)
#pragma unroll
        for (int dt = 0; dt < 8; ++dt)
#pragma unroll
            for (int r = 0; r < 4; ++r)
                pb[(size_t)(j0 + jt * 16 + hq * 4 + r) * D + w * 128 + dt * 16 + cl] =
                    (f16)oacc[jt][dt][r];
    if (w == 0 && l < 32) {
        float2 v; v.x = m_run; v.y = l_run;
        ml[(size_t)ib * N + j0 + l] = v;
    }
}

// ---------------- merge the i-block partials ----------------
__global__ __launch_bounds__(256) void merge_p(
    float* __restrict__ out, const f16* __restrict__ p0,
    const f16* __restrict__ p123, const float2* __restrict__ ml, int nib)
{
    const int idx = blockIdx.x * 256 + threadIdx.x;
    const int j = idx >> 7;
    const int col = (idx & 127) * 4;

    float m_g = NEG;
    for (int ib = 0; ib < nib; ++ib) m_g = fmaxf(m_g, ml[(size_t)ib * N + j].x);
    float L = 0.f;
    float4 acc; acc.x = 0.f; acc.y = 0.f; acc.z = 0.f; acc.w = 0.f;
    for (int ib = 0; ib < nib; ++ib) {
        const float2 a = ml[(size_t)ib * N + j];
        const float e = __expf(a.x - m_g);
        L += e * a.y;
        const f16* pp = (ib == 0) ? p0 : p123 + (size_t)(ib - 1) * ((size_t)N * D);
        const f16x4 h = *(const f16x4*)(pp + (size_t)j * D + col);
        acc.x += e * (float)h.x; acc.y += e * (float)h.y;
        acc.z += e * (float)h.z; acc.w += e * (float)h.w;
    }
    const float inv = (L > 0.f) ? 1.f / L : 0.f;
    float4 r; r.x = acc.x * inv; r.y = acc.y * inv; r.z = acc.z * inv; r.w = acc.w * inv;
    ((float4*)out)[idx] = r;
}

extern "C" void kernel_launch(void* const* d_in, const int* in_sizes, int n_in,
                              void* d_out, int out_size, void* d_ws, size_t ws_size,
                              hipStream_t stream) {
    const float* ns  = (const float*)d_in[0];
    const int*   adj = (const int*)d_in[1];
    const float* Wq  = (const float*)d_in[2];
    const float* Wk  = (const float*)d_in[3];
    const float* Wv  = (const float*)d_in[4];

    char* ws = (char*)d_ws;
    f16*   Xh   = (f16*)(ws + XH_OFF);
    f16*   Wqh  = (f16*)(ws + WQH_OFF);
    f16*   Wkh  = (f16*)(ws + WKH_OFF);
    f16*   Wvh  = (f16*)(ws + WVH_OFF);
    f16*   qh   = (f16*)(ws + QH_OFF);
    f16*   kh   = (f16*)(ws + KH_OFF);
    f16*   vt   = (f16*)(ws + VT_OFF);
    f16*   p0   = (f16*)(ws + XH_OFF);          // overlays dead XH
    f16*   p123 = (f16*)(ws + P123_OFF);
    float* out  = (float*)d_out;

    const size_t need4 = P123_OFF + 3 * PART_SZ + ML_SZ + ADJ_SZ;
    int nib; size_t ml_off;
    if (ws_size >= need4) { nib = 4; ml_off = P123_OFF + 3 * PART_SZ; }
    else                  { nib = 2; ml_off = P123_OFF + 1 * PART_SZ; }
    float2* mlb  = (float2*)(ws + ml_off);
    u64*    adjb = (u64*)(ws + ml_off + ML_SZ);

    cvt_fp16<<<4864, 256, 0, stream>>>(ns, Wq, Wk, Wv, Xh, Wqh, Wkh, Wvh);
    qkv_mfma<<<dim3(4, 64, 3), 256, 0, stream>>>(Xh, Wqh, Wkh, Wvh, qh, kh, vt);
    pack_adj<<<dim3(128, 2), 256, 0, stream>>>(adj, adjb);
    attn_v5<<<256 * nib, 256, 0, stream>>>(qh, kh, vt, adjb, p0, p123, mlb);
    merge_p<<<4096, 256, 0, stream>>>(out, p0, p123, mlb, nib);
}

// Round 12
// 702.511 us; speedup vs baseline: 1.2705x; 1.2705x over previous
//
#include <hip/hip_runtime.h>
#include <stdint.h>

#define N 8192
#define D 512
#define NEG -1e30f

typedef _Float16 f16;
typedef f16 f16x4 __attribute__((ext_vector_type(4)));
typedef f16 f16x8 __attribute__((ext_vector_type(8)));
typedef float f32x4v __attribute__((ext_vector_type(4)));
typedef float f32x16 __attribute__((ext_vector_type(16)));
typedef unsigned long long u64;

// ---- workspace layout (bytes) ----
#define XH_OFF   0ull
#define WQH_OFF  (XH_OFF + 8192ull * 512 * 2)
#define WKH_OFF  (WQH_OFF + 512ull * 512 * 2)
#define WVH_OFF  (WKH_OFF + 512ull * 512 * 2)
#define QH_OFF   (WVH_OFF + 512ull * 512 * 2)
#define KH_OFF   (QH_OFF + 8192ull * 512 * 2)
#define VT_OFF   (KH_OFF + 8192ull * 512 * 2)
#define PART_SZ  (8192ull * 512 * 2)                // one fp16 partial, 8 MB
#define P123_OFF (VT_OFF + 8192ull * 512 * 2)
#define ML_SZ    (4ull * N * 8)                     // float2[4][N]
#define ADJ_SZ   (128ull * N * 8)                   // u64 bitmap, 8 MB

// ---- attn_v6 LDS map (77,824 B dynamic -> 2 blocks/CU) ----
#define QROW     1040
#define PROW     144
#define PSB_OFF  66560                    // 64*1040
#define MST_OFF  75776                    // [4][64] f32
#define LST_OFF  76800
#define LDSB_V6  77824

// ---------------- fp32 -> fp16 conversion ----------------
__global__ __launch_bounds__(256) void cvt_fp16(
    const float* __restrict__ X,
    const float* __restrict__ Wq, const float* __restrict__ Wk, const float* __restrict__ Wv,
    f16* __restrict__ Xh,
    f16* __restrict__ Wqh, f16* __restrict__ Wkh, f16* __restrict__ Wvh)
{
    const int idx = blockIdx.x * 256 + threadIdx.x;
    const float* src; f16* dst; int off;
    if (idx < 1048576)      { src = X;  dst = Xh;  off = idx; }
    else if (idx < 1114112) { src = Wq; dst = Wqh; off = idx - 1048576; }
    else if (idx < 1179648) { src = Wk; dst = Wkh; off = idx - 1114112; }
    else                    { src = Wv; dst = Wvh; off = idx - 1179648; }
    const float4 v = ((const float4*)src)[off];
    f16x4 h; h.x = (f16)v.x; h.y = (f16)v.y; h.z = (f16)v.z; h.w = (f16)v.w;
    *(f16x4*)(dst + (size_t)off * 4) = h;
}

// ---------------- QKV via MFMA (unchanged) ----------------
__global__ __launch_bounds__(256) void qkv_mfma(
    const f16* __restrict__ Xh,
    const f16* __restrict__ Wqh, const f16* __restrict__ Wkh, const f16* __restrict__ Wvh,
    f16* __restrict__ qh, f16* __restrict__ kh, f16* __restrict__ vt)
{
    const int t    = threadIdx.x;
    const int w    = t >> 6;
    const int lane = t & 63;
    const int lo   = lane & 31;
    const int hi   = lane >> 5;
    const int z    = blockIdx.z;

    int m0, c0; const f16 *Ap, *Bp; f16* Yp; size_t ldy;
    if (z == 2) {
        m0 = blockIdx.x * 128 + w * 32; c0 = blockIdx.y * 128;
        Ap = Wvh; Bp = Xh; Yp = vt; ldy = N;
    } else {
        m0 = blockIdx.y * 128 + w * 32; c0 = blockIdx.x * 128;
        Ap = Xh; Bp = z ? Wkh : Wqh; Yp = z ? kh : qh; ldy = D;
    }

    const f16* arow = Ap + (size_t)(m0 + lo) * D + hi * 8;
    const f16* brow[4];
#pragma unroll
    for (int nn = 0; nn < 4; ++nn)
        brow[nn] = Bp + (size_t)(c0 + nn * 32 + lo) * D + hi * 8;

    f32x16 acc[4];
#pragma unroll
    for (int nn = 0; nn < 4; ++nn)
#pragma unroll
        for (int e = 0; e < 16; ++e) acc[nn][e] = 0.f;

#pragma unroll 4
    for (int ks = 0; ks < 32; ++ks) {
        const f16x8 a = *(const f16x8*)(arow + ks * 16);
#pragma unroll
        for (int nn = 0; nn < 4; ++nn) {
            const f16x8 b = *(const f16x8*)(brow[nn] + ks * 16);
            acc[nn] = __builtin_amdgcn_mfma_f32_32x32x16_f16(a, b, acc[nn], 0, 0, 0);
        }
    }

#pragma unroll
    for (int nn = 0; nn < 4; ++nn)
#pragma unroll
        for (int r = 0; r < 16; ++r) {
            const int row = m0 + (r & 3) + 8 * (r >> 2) + 4 * hi;
            Yp[(size_t)row * ldy + c0 + nn * 32 + lo] = (f16)acc[nn][r];
        }
}

// ---------------- adjacency bit-pack (proven r11) ----------------
__global__ __launch_bounds__(256) void pack_adj(
    const int* __restrict__ adj, u64* __restrict__ adjb)
{
    const int widx = blockIdx.x;
    const int wv   = threadIdx.x >> 6;
    const int lane = threadIdx.x & 63;
    const int jb   = blockIdx.y * 4096 + wv * 1024;
    const int* src = adj + (size_t)(widx * 64 + lane) * N;
    u64* dst = adjb + (size_t)widx * N;
    for (int jj = 0; jj < 1024; ++jj) {
        const int j = jb + jj;
        const u64 m = __ballot(src[j] != 0);
        if (lane == 0) dst[j] = m;
    }
}

// ---------------- attention v6: v4.1 + bitmap + redundant combine + K prefetch ----------------
// grid = 128 j-tiles (BJ=64) x nib i-blocks = 512 blocks, 256 thr / 4 waves,
// 2 blocks/CU (LDS 77.8 KB). Per tile (BI=64): QK^T waves split i-bands (w*16);
// PV waves split d-bands (w*128). 3 barriers/tile, no single-wave phase.
__global__ __launch_bounds__(256, 2) void attn_v6(
    const f16* __restrict__ qh, const f16* __restrict__ kh,
    const f16* __restrict__ vt, const u64* __restrict__ adjb,
    f16* __restrict__ part0, f16* __restrict__ part123, float2* __restrict__ ml)
{
    extern __shared__ char smem[];
    char*  Qs    = smem;
    char*  Psb   = smem + PSB_OFF;
    float* mstat = (float*)(smem + MST_OFF);
    float* lstat = (float*)(smem + LST_OFF);

    const int t  = threadIdx.x;
    const int w  = t >> 6;
    const int l  = t & 63;
    const int cl = l & 15;
    const int hq = l >> 4;

    // XCD-aware mapping (i-block per XCD pair, bijective j-tile)
    const int nib = gridDim.x >> 7;          // 4 or 2
    const int b   = blockIdx.x;
    const int xcd = b & 7;
    int ib, jt_;
    if (nib == 4) { ib = xcd >> 1; jt_ = (xcd & 1) * 64 + (b >> 3); }
    else          { ib = xcd >> 2; jt_ = (xcd & 3) * 32 + (b >> 3); }
    const int j0    = jt_ * 64;
    const int ibase = ib * (N / nib);
    const int iters = (N / nib) >> 6;

    f16* pb = (ib == 0) ? part0 : part123 + (size_t)(ib - 1) * ((size_t)N * D);

    // ---- stage Q[j0..j0+63] ----
    for (int c = t; c < 64 * 64; c += 256) {
        const int row = c >> 6, off = c & 63;
        f16x8 v = *(const f16x8*)(qh + (size_t)(j0 + row) * D + off * 8);
        *(f16x8*)(Qs + row * QROW + off * 16) = v;
    }
    __syncthreads();

    float m_run = NEG, l_run = 0.f;          // stats for j = l, identical in all waves

    f32x4v oacc[4][8];
#pragma unroll
    for (int jt = 0; jt < 4; ++jt)
#pragma unroll
        for (int dt = 0; dt < 8; ++dt) {
            oacc[jt][dt][0] = 0.f; oacc[jt][dt][1] = 0.f;
            oacc[jt][dt][2] = 0.f; oacc[jt][dt][3] = 0.f;
        }

    // ---- prologue prefetch: tile 0 masks + first-half K ----
    u64   wd[4];
    f16x8 kpre[8];
    {
        const u64* ab = adjb + ((size_t)(ibase >> 6)) * N + j0;
#pragma unroll
        for (int jt = 0; jt < 4; ++jt) wd[jt] = ab[jt * 16 + cl];
        const f16* kp = kh + (size_t)(ibase + w * 16 + cl) * D + hq * 8;
#pragma unroll
        for (int ks = 0; ks < 8; ++ks) kpre[ks] = *(const f16x8*)(kp + ks * 32);
    }

    for (int it = 0; it < iters; ++it) {
        const int i0t = ibase + it * 64;

        // ---- QK^T: wave w = i-band w*16 ----
        f32x4v sacc[4];
#pragma unroll
        for (int jt = 0; jt < 4; ++jt) {
            sacc[jt][0] = 0.f; sacc[jt][1] = 0.f; sacc[jt][2] = 0.f; sacc[jt][3] = 0.f;
        }
        const f16* kp = kh + (size_t)(i0t + w * 16 + cl) * D + hq * 8;
#pragma unroll
        for (int ks = 0; ks < 16; ++ks) {
            const f16x8 kf = (ks < 8) ? kpre[ks] : *(const f16x8*)(kp + ks * 32);
#pragma unroll
            for (int jt = 0; jt < 4; ++jt) {
                const f16x8 qf = *(const f16x8*)(Qs + (jt * 16 + cl) * QROW + ks * 64 + hq * 16);
                sacc[jt] = __builtin_amdgcn_mfma_f32_16x16x32_f16(kf, qf, sacc[jt], 0, 0, 0);
            }
        }

        // ---- mask (bitmap) + band stats; lane holds S^T[i=band+hq*4+r][j=jt*16+cl] ----
        float pe[4][4], mb4[4];
#pragma unroll
        for (int jt = 0; jt < 4; ++jt) {
            const uint32_t sub = (uint32_t)(wd[jt] >> (w * 16 + hq * 4)) & 0xFu;
            float s[4];
#pragma unroll
            for (int r = 0; r < 4; ++r) s[r] = ((sub >> r) & 1) ? sacc[jt][r] : NEG;
            float m4 = fmaxf(fmaxf(s[0], s[1]), fmaxf(s[2], s[3]));
            m4 = fmaxf(m4, __shfl_xor(m4, 16, 64));
            m4 = fmaxf(m4, __shfl_xor(m4, 32, 64));
            mb4[jt] = m4;
            float pl = 0.f;
#pragma unroll
            for (int r = 0; r < 4; ++r) {
                const float p = (s[r] > -1e29f) ? __expf(s[r] - m4) : 0.f;
                pe[jt][r] = p;
                pl += p;
            }
            pl += __shfl_xor(pl, 16, 64);
            pl += __shfl_xor(pl, 32, 64);
            if (l < 16) {
                mstat[w * 64 + jt * 16 + l] = m4;
                lstat[w * 64 + jt * 16 + l] = pl;
            }
        }
        __syncthreads();                     // [A] stats visible

        // ---- redundant combine (j = l, all waves identical) ----
        float sc;
        {
            const float b0 = mstat[l],       s0 = lstat[l];
            const float b1 = mstat[64 + l],  s1 = lstat[64 + l];
            const float b2 = mstat[128 + l], s2 = lstat[128 + l];
            const float b3 = mstat[192 + l], s3 = lstat[192 + l];
            const float mn = fmaxf(m_run, fmaxf(fmaxf(b0, b1), fmaxf(b2, b3)));
            sc = __expf(m_run - mn);
            l_run = l_run * sc + s0 * __expf(b0 - mn) + s1 * __expf(b1 - mn)
                               + s2 * __expf(b2 - mn) + s3 * __expf(b3 - mn);
            m_run = mn;
        }

        // ---- P fix to global max + write to LDS ----
#pragma unroll
        for (int jt = 0; jt < 4; ++jt) {
            const float mnj = __shfl(m_run, jt * 16 + cl, 64);
            const float f   = __expf(mb4[jt] - mnj);
            union { f16 h[4]; uint2 u2; } pc;
#pragma unroll
            for (int r = 0; r < 4; ++r) pc.h[r] = (f16)(pe[jt][r] * f);
            *(uint2*)(Psb + (jt * 16 + cl) * PROW + (w * 16 + hq * 4) * 2) = pc.u2;
        }

        // ---- rescale O (skip when no row max moved — uniform across waves) ----
        if (__any(sc != 1.f)) {
#pragma unroll
            for (int jt = 0; jt < 4; ++jt)
#pragma unroll
                for (int r = 0; r < 4; ++r) {
                    const float scr = __shfl(sc, jt * 16 + hq * 4 + r, 64);
#pragma unroll
                    for (int dt = 0; dt < 8; ++dt) oacc[jt][dt][r] *= scr;
                }
        }
        __syncthreads();                     // [B] P ready

        // ---- prefetch next tile's masks + first-half K (hides under PV) ----
        if (it + 1 < iters) {
            const int i0n = i0t + 64;
            const u64* abn = adjb + ((size_t)(i0n >> 6)) * N + j0;
#pragma unroll
            for (int jt = 0; jt < 4; ++jt) wd[jt] = abn[jt * 16 + cl];
            const f16* kpn = kh + (size_t)(i0n + w * 16 + cl) * D + hq * 8;
#pragma unroll
            for (int ks = 0; ks < 8; ++ks) kpre[ks] = *(const f16x8*)(kpn + ks * 32);
        }

        // ---- PV: wave w = d-band w*128 ----
        f16x8 pa[4][2];
#pragma unroll
        for (int jt = 0; jt < 4; ++jt)
#pragma unroll
            for (int k2 = 0; k2 < 2; ++k2)
                pa[jt][k2] = *(const f16x8*)(Psb + (jt * 16 + cl) * PROW + k2 * 64 + hq * 16);

#pragma unroll
        for (int dt = 0; dt < 8; ++dt) {
            const f16* vp = vt + (size_t)(w * 128 + dt * 16 + cl) * N + i0t + hq * 8;
#pragma unroll
            for (int k2 = 0; k2 < 2; ++k2) {
                const f16x8 vf = *(const f16x8*)(vp + k2 * 32);
#pragma unroll
                for (int jt = 0; jt < 4; ++jt)
                    oacc[jt][dt] = __builtin_amdgcn_mfma_f32_16x16x32_f16(pa[jt][k2], vf, oacc[jt][dt], 0, 0, 0);
            }
        }
        __syncthreads();                     // [D] P consumed
    }

    // ---- store fp16 unnormalized partial: row j = jt*16+hq*4+r, col = w*128+dt*16+cl ----
#pragma unroll
    for (int jt = 0; jt < 4; ++jt)
#pragma unroll
        for (int dt = 0; dt < 8; ++dt)
#pragma unroll
            for (int r = 0; r < 4; ++r)
                pb[(size_t)(j0 + jt * 16 + hq * 4 + r) * D + w * 128 + dt * 16 + cl] =
                    (f16)oacc[jt][dt][r];
    if (t < 64) {
        float2 v; v.x = m_run; v.y = l_run;
        ml[(size_t)ib * N + j0 + l] = v;
    }
}

// ---------------- merge the i-block partials ----------------
__global__ __launch_bounds__(256) void merge_p(
    float* __restrict__ out, const f16* __restrict__ p0,
    const f16* __restrict__ p123, const float2* __restrict__ ml, int nib)
{
    const int idx = blockIdx.x * 256 + threadIdx.x;
    const int j = idx >> 7;
    const int col = (idx & 127) * 4;

    float m_g = NEG;
    for (int ib = 0; ib < nib; ++ib) m_g = fmaxf(m_g, ml[(size_t)ib * N + j].x);
    float L = 0.f;
    float4 acc; acc.x = 0.f; acc.y = 0.f; acc.z = 0.f; acc.w = 0.f;
    for (int ib = 0; ib < nib; ++ib) {
        const float2 a = ml[(size_t)ib * N + j];
        const float e = __expf(a.x - m_g);
        L += e * a.y;
        const f16* pp = (ib == 0) ? p0 : p123 + (size_t)(ib - 1) * ((size_t)N * D);
        const f16x4 h = *(const f16x4*)(pp + (size_t)j * D + col);
        acc.x += e * (float)h.x; acc.y += e * (float)h.y;
        acc.z += e * (float)h.z; acc.w += e * (float)h.w;
    }
    const float inv = (L > 0.f) ? 1.f / L : 0.f;
    float4 r; r.x = acc.x * inv; r.y = acc.y * inv; r.z = acc.z * inv; r.w = acc.w * inv;
    ((float4*)out)[idx] = r;
}

extern "C" void kernel_launch(void* const* d_in, const int* in_sizes, int n_in,
                              void* d_out, int out_size, void* d_ws, size_t ws_size,
                              hipStream_t stream) {
    const float* ns  = (const float*)d_in[0];
    const int*   adj = (const int*)d_in[1];
    const float* Wq  = (const float*)d_in[2];
    const float* Wk  = (const float*)d_in[3];
    const float* Wv  = (const float*)d_in[4];

    char* ws = (char*)d_ws;
    f16*   Xh   = (f16*)(ws + XH_OFF);
    f16*   Wqh  = (f16*)(ws + WQH_OFF);
    f16*   Wkh  = (f16*)(ws + WKH_OFF);
    f16*   Wvh  = (f16*)(ws + WVH_OFF);
    f16*   qh   = (f16*)(ws + QH_OFF);
    f16*   kh   = (f16*)(ws + KH_OFF);
    f16*   vt   = (f16*)(ws + VT_OFF);
    f16*   p0   = (f16*)(ws + XH_OFF);          // overlays dead XH
    f16*   p123 = (f16*)(ws + P123_OFF);
    float* out  = (float*)d_out;

    const size_t need4 = P123_OFF + 3 * PART_SZ + ML_SZ + ADJ_SZ;
    int nib; size_t ml_off;
    if (ws_size >= need4) { nib = 4; ml_off = P123_OFF + 3 * PART_SZ; }
    else                  { nib = 2; ml_off = P123_OFF + 1 * PART_SZ; }
    float2* mlb  = (float2*)(ws + ml_off);
    u64*    adjb = (u64*)(ws + ml_off + ML_SZ);

    (void)hipFuncSetAttribute((const void*)attn_v6,
                              hipFuncAttributeMaxDynamicSharedMemorySize, LDSB_V6);

    cvt_fp16<<<4864, 256, 0, stream>>>(ns, Wq, Wk, Wv, Xh, Wqh, Wkh, Wvh);
    qkv_mfma<<<dim3(4, 64, 3), 256, 0, stream>>>(Xh, Wqh, Wkh, Wvh, qh, kh, vt);
    pack_adj<<<dim3(128, 2), 256, 0, stream>>>(adj, adjb);
    attn_v6<<<128 * nib, 256, LDSB_V6, stream>>>(qh, kh, vt, adjb, p0, p123, mlb);
    merge_p<<<4096, 256, 0, stream>>>(out, p0, p123, mlb, nib);
}

// Round 13
// 688.695 us; speedup vs baseline: 1.2960x; 1.0201x over previous
//
#include <hip/hip_runtime.h>
#include <stdint.h>

#define N 8192
#define D 512
#define NEG -1e30f

typedef _Float16 f16;
typedef f16 f16x4 __attribute__((ext_vector_type(4)));
typedef f16 f16x8 __attribute__((ext_vector_type(8)));
typedef float f32x4v __attribute__((ext_vector_type(4)));
typedef float f32x16 __attribute__((ext_vector_type(16)));
typedef unsigned long long u64;

// ---- workspace layout (bytes) ----
#define XH_OFF   0ull
#define WQH_OFF  (XH_OFF + 8192ull * 512 * 2)
#define WKH_OFF  (WQH_OFF + 512ull * 512 * 2)
#define WVH_OFF  (WKH_OFF + 512ull * 512 * 2)
#define QH_OFF   (WVH_OFF + 512ull * 512 * 2)
#define KH_OFF   (QH_OFF + 8192ull * 512 * 2)
#define VT_OFF   (KH_OFF + 8192ull * 512 * 2)
#define PART_SZ  (8192ull * 512 * 2)                // one fp16 partial, 8 MB
#define P123_OFF (VT_OFF + 8192ull * 512 * 2)
#define ML_SZ    (4ull * N * 8)                     // float2[4][N]
#define ADJ_SZ   (128ull * N * 8)                   // u64 bitmap, 8 MB

// ---------------- fp32 -> fp16 conversion ----------------
__global__ __launch_bounds__(256) void cvt_fp16(
    const float* __restrict__ X,
    const float* __restrict__ Wq, const float* __restrict__ Wk, const float* __restrict__ Wv,
    f16* __restrict__ Xh,
    f16* __restrict__ Wqh, f16* __restrict__ Wkh, f16* __restrict__ Wvh)
{
    const int idx = blockIdx.x * 256 + threadIdx.x;
    const float* src; f16* dst; int off;
    if (idx < 1048576)      { src = X;  dst = Xh;  off = idx; }
    else if (idx < 1114112) { src = Wq; dst = Wqh; off = idx - 1048576; }
    else if (idx < 1179648) { src = Wk; dst = Wkh; off = idx - 1114112; }
    else                    { src = Wv; dst = Wvh; off = idx - 1179648; }
    const float4 v = ((const float4*)src)[off];
    f16x4 h; h.x = (f16)v.x; h.y = (f16)v.y; h.z = (f16)v.z; h.w = (f16)v.w;
    *(f16x4*)(dst + (size_t)off * 4) = h;
}

// ---------------- QKV via MFMA (unchanged) ----------------
__global__ __launch_bounds__(256) void qkv_mfma(
    const f16* __restrict__ Xh,
    const f16* __restrict__ Wqh, const f16* __restrict__ Wkh, const f16* __restrict__ Wvh,
    f16* __restrict__ qh, f16* __restrict__ kh, f16* __restrict__ vt)
{
    const int t    = threadIdx.x;
    const int w    = t >> 6;
    const int lane = t & 63;
    const int lo   = lane & 31;
    const int hi   = lane >> 5;
    const int z    = blockIdx.z;

    int m0, c0; const f16 *Ap, *Bp; f16* Yp; size_t ldy;
    if (z == 2) {
        m0 = blockIdx.x * 128 + w * 32; c0 = blockIdx.y * 128;
        Ap = Wvh; Bp = Xh; Yp = vt; ldy = N;
    } else {
        m0 = blockIdx.y * 128 + w * 32; c0 = blockIdx.x * 128;
        Ap = Xh; Bp = z ? Wkh : Wqh; Yp = z ? kh : qh; ldy = D;
    }

    const f16* arow = Ap + (size_t)(m0 + lo) * D + hi * 8;
    const f16* brow[4];
#pragma unroll
    for (int nn = 0; nn < 4; ++nn)
        brow[nn] = Bp + (size_t)(c0 + nn * 32 + lo) * D + hi * 8;

    f32x16 acc[4];
#pragma unroll
    for (int nn = 0; nn < 4; ++nn)
#pragma unroll
        for (int e = 0; e < 16; ++e) acc[nn][e] = 0.f;

#pragma unroll 4
    for (int ks = 0; ks < 32; ++ks) {
        const f16x8 a = *(const f16x8*)(arow + ks * 16);
#pragma unroll
        for (int nn = 0; nn < 4; ++nn) {
            const f16x8 b = *(const f16x8*)(brow[nn] + ks * 16);
            acc[nn] = __builtin_amdgcn_mfma_f32_32x32x16_f16(a, b, acc[nn], 0, 0, 0);
        }
    }

#pragma unroll
    for (int nn = 0; nn < 4; ++nn)
#pragma unroll
        for (int r = 0; r < 16; ++r) {
            const int row = m0 + (r & 3) + 8 * (r >> 2) + 4 * hi;
            Yp[(size_t)row * ldy + c0 + nn * 32 + lo] = (f16)acc[nn][r];
        }
}

// ---------------- adjacency bit-pack, COALESCED ----------------
// thread <-> (iword, j): lane-contiguous j -> every load instr = 256B coalesced.
// adjb[iw][j] bit b = adj[iw*64+b][j]  (same layout as r11/r12 consumers).
__global__ __launch_bounds__(256) void pack_adj(
    const int* __restrict__ adj, u64* __restrict__ adjb)
{
    const int idx = blockIdx.x * 256 + threadIdx.x;   // 1,048,576 total
    const int j   = idx & (N - 1);
    const int iw  = idx >> 13;                        // 0..127
    const int* src = adj + (size_t)iw * 64 * N + j;
    u64 bits = 0;
#pragma unroll 8
    for (int i2 = 0; i2 < 64; ++i2)
        bits |= (u64)(src[(size_t)i2 * N] != 0) << i2;
    adjb[(size_t)iw * N + j] = bits;
}

// ---------------- attention v7: BJ=32/BI=64 cooperative, 4 blocks/CU exact fit ----------------
// grid = 256 j-tiles x nib i-blocks (nib=4 -> 1024 blocks = 4/CU x 256 CU exact).
// 256 thr / 4 waves. Per tile (BI=64): QK^T waves split i-bands (w*16); PV waves
// split d-bands (w*128). Redundant all-wave combine (m/l in regs, j = l&31).
// 3 barriers/tile. LDS 37.9 KB: XOR-swizzled Qs (32K) + swizzled Psb (4K) + stats.
__global__ __launch_bounds__(256, 4) void attn_v7(
    const f16* __restrict__ qh, const f16* __restrict__ kh,
    const f16* __restrict__ vt, const u64* __restrict__ adjb,
    f16* __restrict__ part0, f16* __restrict__ part123, float2* __restrict__ ml)
{
    __shared__ char  Qs[32 * 1024];     // 32,768, XOR-16B swizzle by (row&7)
    __shared__ char  Psb[32 * 128];     //  4,096, XOR-16B swizzle by (row&7)
    __shared__ float mstat[4 * 32];
    __shared__ float lstat[4 * 32];

    const int t  = threadIdx.x;
    const int w  = t >> 6;
    const int l  = t & 63;
    const int cl = l & 15;
    const int hq = l >> 4;

    // XCD-aware mapping (i-block per XCD group, bijective j-tile)
    const int nib = gridDim.x >> 8;          // 4 or 2
    const int b   = blockIdx.x;
    const int xcd = b & 7;
    const int u   = b >> 3;
    int ib, jt_;
    if (nib == 4) { ib = xcd >> 1; jt_ = (xcd & 1) * 128 + u; }
    else          { ib = xcd >> 2; jt_ = (xcd & 3) * 64 + u; }
    const int j0    = jt_ * 32;
    const int ibase = ib * (N / nib);
    const int iters = (N / nib) >> 6;        // 32 (nib=4) or 64 (nib=2)

    f16* pb = (ib == 0) ? part0 : part123 + (size_t)(ib - 1) * ((size_t)N * D);

    // ---- stage Q[j0..j0+31] (swizzled) ----
    for (int c = t; c < 32 * 64; c += 256) {
        const int row = c >> 6, off = c & 63;
        f16x8 v = *(const f16x8*)(qh + (size_t)(j0 + row) * D + off * 8);
        *(f16x8*)(Qs + ((row * 1024 + off * 16) ^ ((row & 7) << 4))) = v;
    }
    __syncthreads();

    float m_run = NEG, l_run = 0.f;          // stats for j = l&31, identical in all waves

    f32x4v oacc[2][8];                       // [jt][dt], 64 VGPR
#pragma unroll
    for (int jt = 0; jt < 2; ++jt)
#pragma unroll
        for (int dt = 0; dt < 8; ++dt) {
            oacc[jt][dt][0] = 0.f; oacc[jt][dt][1] = 0.f;
            oacc[jt][dt][2] = 0.f; oacc[jt][dt][3] = 0.f;
        }

    const int qswz = (cl & 7) << 4;

    for (int it = 0; it < iters; ++it) {
        const int i0t = ibase + it * 64;

        // ---- adjacency bitmap words (L2-resident, 2x 8B per lane) ----
        const u64* ab = adjb + ((size_t)(i0t >> 6)) * N + j0;
        u64 wd[2];
        wd[0] = ab[cl];
        wd[1] = ab[16 + cl];

        // ---- QK^T: wave w = i-band w*16; S^T[i 16][j 32] ----
        f32x4v sacc[2];
#pragma unroll
        for (int jt = 0; jt < 2; ++jt) {
            sacc[jt][0] = 0.f; sacc[jt][1] = 0.f; sacc[jt][2] = 0.f; sacc[jt][3] = 0.f;
        }
        const f16* kp = kh + (size_t)(i0t + w * 16 + cl) * D + hq * 8;
#pragma unroll
        for (int ks = 0; ks < 16; ++ks) {
            const f16x8 kf = *(const f16x8*)(kp + ks * 32);
#pragma unroll
            for (int jt = 0; jt < 2; ++jt) {
                const f16x8 qf = *(const f16x8*)(Qs +
                    (((jt * 16 + cl) * 1024 + ks * 64 + hq * 16) ^ qswz));
                sacc[jt] = __builtin_amdgcn_mfma_f32_16x16x32_f16(kf, qf, sacc[jt], 0, 0, 0);
            }
        }

        // ---- mask + band stats; lane holds S^T[i=w*16+hq*4+r][j=jt*16+cl] ----
        float pe[2][4], mb4[2];
#pragma unroll
        for (int jt = 0; jt < 2; ++jt) {
            const uint32_t sub = (uint32_t)(wd[jt] >> (w * 16 + hq * 4)) & 0xFu;
            float s[4];
#pragma unroll
            for (int r = 0; r < 4; ++r) s[r] = ((sub >> r) & 1) ? sacc[jt][r] : NEG;
            float m4 = fmaxf(fmaxf(s[0], s[1]), fmaxf(s[2], s[3]));
            m4 = fmaxf(m4, __shfl_xor(m4, 16, 64));
            m4 = fmaxf(m4, __shfl_xor(m4, 32, 64));
            mb4[jt] = m4;
            float pl = 0.f;
#pragma unroll
            for (int r = 0; r < 4; ++r) {
                const float p = (s[r] > -1e29f) ? __expf(s[r] - m4) : 0.f;
                pe[jt][r] = p;
                pl += p;
            }
            pl += __shfl_xor(pl, 16, 64);
            pl += __shfl_xor(pl, 32, 64);
            if (l < 16) {
                mstat[w * 32 + jt * 16 + l] = m4;
                lstat[w * 32 + jt * 16 + l] = pl;
            }
        }
        __syncthreads();                     // [A] stats visible

        // ---- redundant combine (j = l&31, identical in all waves) ----
        float sc;
        {
            const int jj = l & 31;
            const float b0 = mstat[jj],      s0 = lstat[jj];
            const float b1 = mstat[32 + jj], s1 = lstat[32 + jj];
            const float b2 = mstat[64 + jj], s2 = lstat[64 + jj];
            const float b3 = mstat[96 + jj], s3 = lstat[96 + jj];
            const float mn = fmaxf(m_run, fmaxf(fmaxf(b0, b1), fmaxf(b2, b3)));
            sc = __expf(m_run - mn);
            l_run = l_run * sc + s0 * __expf(b0 - mn) + s1 * __expf(b1 - mn)
                               + s2 * __expf(b2 - mn) + s3 * __expf(b3 - mn);
            m_run = mn;
        }

        // ---- P fix to global max + write to swizzled wave slab region ----
#pragma unroll
        for (int jt = 0; jt < 2; ++jt) {
            const float mnj = __shfl(m_run, jt * 16 + cl, 64);
            const float f   = __expf(mb4[jt] - mnj);
            union { f16 h[4]; uint2 u2; } pc;
#pragma unroll
            for (int r = 0; r < 4; ++r) pc.h[r] = (f16)(pe[jt][r] * f);
            *(uint2*)(Psb + (((jt * 16 + cl) * 128 + (w * 16 + hq * 4) * 2) ^ qswz)) = pc.u2;
        }

        // ---- rescale O (skip when no row max moved) ----
        if (__any(sc != 1.f)) {
#pragma unroll
            for (int jt = 0; jt < 2; ++jt)
#pragma unroll
                for (int r = 0; r < 4; ++r) {
                    const float scr = __shfl(sc, jt * 16 + hq * 4 + r, 64);
#pragma unroll
                    for (int dt = 0; dt < 8; ++dt) oacc[jt][dt][r] *= scr;
                }
        }
        __syncthreads();                     // [B] P ready

        // ---- PV: wave w = d-band w*128 ----
        f16x8 pa[2][2];
#pragma unroll
        for (int jt = 0; jt < 2; ++jt)
#pragma unroll
            for (int k2 = 0; k2 < 2; ++k2)
                pa[jt][k2] = *(const f16x8*)(Psb +
                    (((jt * 16 + cl) * 128 + k2 * 64 + hq * 16) ^ qswz));

#pragma unroll
        for (int dt = 0; dt < 8; ++dt) {
            const f16* vp = vt + (size_t)(w * 128 + dt * 16 + cl) * N + i0t + hq * 8;
#pragma unroll
            for (int k2 = 0; k2 < 2; ++k2) {
                const f16x8 vf = *(const f16x8*)(vp + k2 * 32);
#pragma unroll
                for (int jt = 0; jt < 2; ++jt)
                    oacc[jt][dt] = __builtin_amdgcn_mfma_f32_16x16x32_f16(pa[jt][k2], vf, oacc[jt][dt], 0, 0, 0);
            }
        }
        __syncthreads();                     // [D] P consumed
    }

    // ---- store fp16 unnormalized partial: row j = jt*16+hq*4+r, col = w*128+dt*16+cl ----
#pragma unroll
    for (int jt = 0; jt < 2; ++jt)
#pragma unroll
        for (int dt = 0; dt < 8; ++dt)
#pragma unroll
            for (int r = 0; r < 4; ++r)
                pb[(size_t)(j0 + jt * 16 + hq * 4 + r) * D + w * 128 + dt * 16 + cl] =
                    (f16)oacc[jt][dt][r];
    if (w == 0 && l < 32) {
        float2 v; v.x = m_run; v.y = l_run;
        ml[(size_t)ib * N + j0 + l] = v;
    }
}

// ---------------- merge the i-block partials ----------------
__global__ __launch_bounds__(256) void merge_p(
    float* __restrict__ out, const f16* __restrict__ p0,
    const f16* __restrict__ p123, const float2* __restrict__ ml, int nib)
{
    const int idx = blockIdx.x * 256 + threadIdx.x;
    const int j = idx >> 7;
    const int col = (idx & 127) * 4;

    float m_g = NEG;
    for (int ib = 0; ib < nib; ++ib) m_g = fmaxf(m_g, ml[(size_t)ib * N + j].x);
    float L = 0.f;
    float4 acc; acc.x = 0.f; acc.y = 0.f; acc.z = 0.f; acc.w = 0.f;
    for (int ib = 0; ib < nib; ++ib) {
        const float2 a = ml[(size_t)ib * N + j];
        const float e = __expf(a.x - m_g);
        L += e * a.y;
        const f16* pp = (ib == 0) ? p0 : p123 + (size_t)(ib - 1) * ((size_t)N * D);
        const f16x4 h = *(const f16x4*)(pp + (size_t)j * D + col);
        acc.x += e * (float)h.x; acc.y += e * (float)h.y;
        acc.z += e * (float)h.z; acc.w += e * (float)h.w;
    }
    const float inv = (L > 0.f) ? 1.f / L : 0.f;
    float4 r; r.x = acc.x * inv; r.y = acc.y * inv; r.z = acc.z * inv; r.w = acc.w * inv;
    ((float4*)out)[idx] = r;
}

extern "C" void kernel_launch(void* const* d_in, const int* in_sizes, int n_in,
                              void* d_out, int out_size, void* d_ws, size_t ws_size,
                              hipStream_t stream) {
    const float* ns  = (const float*)d_in[0];
    const int*   adj = (const int*)d_in[1];
    const float* Wq  = (const float*)d_in[2];
    const float* Wk  = (const float*)d_in[3];
    const float* Wv  = (const float*)d_in[4];

    char* ws = (char*)d_ws;
    f16*   Xh   = (f16*)(ws + XH_OFF);
    f16*   Wqh  = (f16*)(ws + WQH_OFF);
    f16*   Wkh  = (f16*)(ws + WKH_OFF);
    f16*   Wvh  = (f16*)(ws + WVH_OFF);
    f16*   qh   = (f16*)(ws + QH_OFF);
    f16*   kh   = (f16*)(ws + KH_OFF);
    f16*   vt   = (f16*)(ws + VT_OFF);
    f16*   p0   = (f16*)(ws + XH_OFF);          // overlays dead XH
    f16*   p123 = (f16*)(ws + P123_OFF);
    float* out  = (float*)d_out;

    const size_t need4 = P123_OFF + 3 * PART_SZ + ML_SZ + ADJ_SZ;
    int nib; size_t ml_off;
    if (ws_size >= need4) { nib = 4; ml_off = P123_OFF + 3 * PART_SZ; }
    else                  { nib = 2; ml_off = P123_OFF + 1 * PART_SZ; }
    float2* mlb  = (float2*)(ws + ml_off);
    u64*    adjb = (u64*)(ws + ml_off + ML_SZ);

    cvt_fp16<<<4864, 256, 0, stream>>>(ns, Wq, Wk, Wv, Xh, Wqh, Wkh, Wvh);
    qkv_mfma<<<dim3(4, 64, 3), 256, 0, stream>>>(Xh, Wqh, Wkh, Wvh, qh, kh, vt);
    pack_adj<<<4096, 256, 0, stream>>>(adj, adjb);
    attn_v7<<<256 * nib, 256, 0, stream>>>(qh, kh, vt, adjb, p0, p123, mlb);
    merge_p<<<4096, 256, 0, stream>>>(out, p0, p123, mlb, nib);
}